// Round 16
// baseline (1038.663 us; speedup 1.0000x reference)
//
#include <hip/hip_runtime.h>
#include <cstdint>
#include <cstddef>

#define IMPOSSIBLE -10000.0f
#define INV_LN2 1.44269504088896340736f
#define LN2 0.69314718055994530942f

constexpr int B = 64;
constexpr int T = 2048;
constexpr int N = 128;
constexpr int WSLOT = 132;   // 128 mid-vector + 1 scale + pad
constexpr int GROUPS = 4;    // independent 4-wave chain-groups per block

typedef _Float16 h2 __attribute__((ext_vector_type(2)));
typedef _Float16 h8 __attribute__((ext_vector_type(8)));

typedef __attribute__((address_space(3))) uint32_t lds_u32_t;
typedef __attribute__((address_space(1))) const uint32_t g_u32_t;

__device__ __forceinline__ void gload_lds4(const void* g, void* l) {
    __builtin_amdgcn_global_load_lds((g_u32_t*)g, (lds_u32_t*)l, 4, 0, 0);
}

struct SmemT {
    __align__(16) _Float16 p_buf[2][128];
    __align__(16) float ring_em[9][128];
    __align__(16) int ring_tg[9][128];
    float wred[4];
    int lred[4];
    int nred;
};

// r15 (bidirectional, fully specialized) + TLP: 4 independent chain-groups
// per block (16 waves, 1024 thr) -> 4 waves/SIMD so other groups issue
// during one group's latency gaps (r15 ran 1 wave/SIMD, ~600cy/step idle).
// Blocks are direction- and channel-pure -> all templates block-uniform;
// shared s_barrier has identical count across groups (FM: literal trips).
// Non-FM fallback: block-max trip count + per-group 'active' guards.
template<bool FWD, bool SUP, bool FM>
__device__ __forceinline__ void run_chain(
    SmemT& sm,
    const float* __restrict__ embase,
    const int* __restrict__ tgbase,
    const float* __restrict__ transitions,
    const int* __restrict__ forb,
    const float* __restrict__ bnd_tr,
    const int* __restrict__ bnd_forb,
    const int tlast_rt,
    const int nrun_rt,     // block-uniform trip count (non-FM)
    float* __restrict__ wsl)
{
    const int tid = (int)threadIdx.x;
    const int gtid = tid & 255;
    const int gwave = gtid >> 6;
    const int lane = tid & 63;
    const int h = lane >> 5;
    const int j = (gwave << 5) | (lane & 31);

    const int tlast = FM ? (T - 1) : tlast_rt;
    const int mid = tlast >> 1;
    const int nself = FWD ? mid : (tlast - mid);
    const int nrun = FM ? (FWD ? ((T - 1) >> 1) : (T - 1 - ((T - 1) >> 1)))
                        : nrun_rt;

    // ---- E slice in f16 pairs, pre-rotated by lane&7 ----
    h2 e2[32];
    #pragma unroll
    for (int k = 0; k < 8; ++k) {
        const int cch = ((lane & 7) + k) & 7;
        const int ib = (h << 6) + (cch << 3);
        #pragma unroll
        for (int m = 0; m < 4; ++m) {
            const int i0 = ib + (m << 1);
            const int idx0 = FWD ? (i0 * N + j) : (j * N + i0);
            const int idx1 = FWD ? ((i0 + 1) * N + j) : (j * N + i0 + 1);
            const float f0 = forb[idx0] ? 0.0f : __expf(transitions[idx0]);
            const float f1 = forb[idx1] ? 0.0f : __expf(transitions[idx1]);
            e2[(k << 2) + m] = h2{(_Float16)f0, (_Float16)f1};
        }
    }

    // ---- init at boundary ----
    const float bnd = bnd_forb[j] ? IMPOSSIBLE : bnd_tr[j];
    const int r0 = FWD ? 0 : tlast;
    const float em0 = embase[(size_t)r0 * N + j];
    const int tg0 = SUP ? tgbase[(size_t)r0 * N + j] : 1;
    const float v0l = ((tg0 ? em0 : IMPOSSIBLE) + bnd) * INV_LN2;

    float mx = v0l;
    #pragma unroll
    for (int d = 1; d < 64; d <<= 1) mx = fmaxf(mx, __shfl_xor(mx, d));
    if (lane == 0) sm.wred[gwave] = mx;
    __syncthreads();
    mx = fmaxf(fmaxf(sm.wred[0], sm.wred[1]), fmaxf(sm.wred[2], sm.wred[3]));

    float Mtot = rintf(mx);
    const float p0 = exp2f(v0l - Mtot);
    if (h == 0) sm.p_buf[0][j] = (_Float16)p0;

    float svE = FWD ? p0 : __expf(bnd);
    float svM = FWD ? Mtot : 0.0f;

    // ---- prologue DMA: 8 ring rows ahead ----
    if (gwave == 0) {
        #pragma unroll
        for (int s = 1; s <= 8; ++s) {
            int srow, drow;
            if (FWD) {
                srow = s; drow = s & 7;
            } else {
                const int r = tlast - s;
                const int ok = FM ? 1 : (r >= 0);
                srow = ok ? r : 0;
                drow = ok ? (r & 7) : 8;
            }
            const float* gse = embase + (size_t)srow * N + lane;
            gload_lds4(gse, &sm.ring_em[drow][0]);
            gload_lds4(gse + 64, &sm.ring_em[drow][64]);
            if (SUP) {
                const int* gst = tgbase + (size_t)srow * N + lane;
                gload_lds4(gst, &sm.ring_tg[drow][0]);
                gload_lds4(gst + 64, &sm.ring_tg[drow][64]);
            }
        }
        if (SUP) asm volatile("s_waitcnt vmcnt(24)" ::: "memory");
        else     asm volatile("s_waitcnt vmcnt(12)" ::: "memory");
    }
    __syncthreads();

    float fx;
    {
        const int t1 = FWD ? 1 : (tlast - 1);
        const int rr = t1 & 7;
        const float em_n = sm.ring_em[rr][j];
        if (SUP) {
            const int tg_n = sm.ring_tg[rr][j];
            fx = tg_n ? __expf(em_n) : 0.0f;
        } else {
            fx = __expf(em_n);
        }
    }

    const _Float16* pb0 = &sm.p_buf[0][h << 6];
    const _Float16* pb1 = &sm.p_buf[1][h << 6];
    const h2 one2 = h2{(_Float16)1.0f, (_Float16)1.0f};

    #pragma unroll 2
    for (int it = 0; it < nrun; ++it) {
        const bool active = FM ? true : (it < nself);
        const int t = FWD ? (1 + it) : (tlast - 1 - it);

        // raw barrier: drain LDS only; DMAs stay in flight (block-wide sync)
        asm volatile("s_waitcnt lgkmcnt(0)\n\ts_barrier" ::: "memory");

        if (gwave == 0 && active) {
            int srow, drow;
            if (FWD) {
                srow = t + 8; drow = srow & 7;
            } else {
                const int tt = t - 8;
                const int ok = (tt >= 0);
                srow = ok ? tt : 0;
                drow = ok ? (tt & 7) : 8;
            }
            const float* gse = embase + (size_t)srow * N + lane;
            gload_lds4(gse, &sm.ring_em[drow][0]);
            gload_lds4(gse + 64, &sm.ring_em[drow][64]);
            if (SUP) {
                const int* gst = tgbase + (size_t)srow * N + lane;
                gload_lds4(gst, &sm.ring_tg[drow][0]);
                gload_lds4(gst + 64, &sm.ring_tg[drow][64]);
            }
        }

        if (active) {
            const int cur = (it & 1) ^ 1;
            const _Float16* pbase = (cur ^ 1) ? pb1 : pb0;

            h8 pvv[8];
            #pragma unroll
            for (int k = 0; k < 8; ++k) {
                const int cch = ((lane & 7) + k) & 7;
                pvv[k] = *reinterpret_cast<const h8*>(pbase + (cch << 3));
            }

            float acc0 = 0.f, acc1 = 0.f, acc2 = 0.f, acc3 = 0.f;
            float ps0 = 0.f, ps1 = 0.f, ps2 = 0.f, ps3 = 0.f;
            #pragma unroll
            for (int k = 0; k < 8; ++k) {
                const h8 pv = pvv[k];
                const h2 w0 = __builtin_shufflevector(pv, pv, 0, 1);
                const h2 w1 = __builtin_shufflevector(pv, pv, 2, 3);
                const h2 w2 = __builtin_shufflevector(pv, pv, 4, 5);
                const h2 w3 = __builtin_shufflevector(pv, pv, 6, 7);
                acc0 = __builtin_amdgcn_fdot2(w0, e2[(k << 2) + 0], acc0, false);
                acc1 = __builtin_amdgcn_fdot2(w1, e2[(k << 2) + 1], acc1, false);
                acc2 = __builtin_amdgcn_fdot2(w2, e2[(k << 2) + 2], acc2, false);
                acc3 = __builtin_amdgcn_fdot2(w3, e2[(k << 2) + 3], acc3, false);
                ps0 = __builtin_amdgcn_fdot2(w0, one2, ps0, false);
                ps1 = __builtin_amdgcn_fdot2(w1, one2, ps1, false);
                ps2 = __builtin_amdgcn_fdot2(w2, one2, ps2, false);
                ps3 = __builtin_amdgcn_fdot2(w3, one2, ps3, false);
            }
            const float s = (acc0 + acc1) + (acc2 + acc3);
            const float ph = (ps0 + ps1) + (ps2 + ps3);

            float x = s, y = s;
            asm volatile("v_permlane32_swap_b32 %0, %1" : "+v"(x), "+v"(y));
            const float stot = x + y;
            float u = ph, v = ph;
            asm volatile("v_permlane32_swap_b32 %0, %1" : "+v"(u), "+v"(v));
            const float psum = fmaxf(u + v, 1e-30f);

            const float sc = __builtin_amdgcn_rcpf(psum);
            Mtot += __log2f(psum);

            const float na = stot * (fx * sc);
            if (t == mid) {
                svE = FWD ? na : (stot * sc);
                svM = Mtot;
            }

            if (h == 0) sm.p_buf[cur][j] = (_Float16)na;

            const int nt = FWD ? (t + 1) : (t - 1);
            const int rr = nt & 7;
            const float em_n = sm.ring_em[rr][j];
            if (SUP) {
                const int tg_n = sm.ring_tg[rr][j];
                fx = tg_n ? __expf(em_n) : 0.0f;
            } else {
                fx = __expf(em_n);
            }
        }

        if (gwave == 0) {
            if (SUP) asm volatile("s_waitcnt vmcnt(24)" ::: "memory");
            else     asm volatile("s_waitcnt vmcnt(12)" ::: "memory");
        }
    }

    if (h == 0) wsl[j] = svE;
    if (gtid == 0) wsl[128] = svM;
}

template<bool FWD, bool SUP, bool FM>
__device__ __forceinline__ void run_block(
    SmemT* smarr, const int chain0,
    const float* __restrict__ emissions, const int* __restrict__ mask,
    const int* __restrict__ target, const float* __restrict__ transitions,
    const float* __restrict__ bnd_tr, const int* __restrict__ bnd_forb,
    const int* __restrict__ forb, const int* tlasts, const int nrun,
    float* __restrict__ ws, const int dir)
{
    const int tid = (int)threadIdx.x;
    const int grp = tid >> 8;
    const int chain = chain0 + grp;
    const int b = chain & 63;
    const float* embase = emissions + (size_t)b * T * N;
    const int* tgbase = target + (size_t)b * T * N;
    float* wsl = ws + (size_t)(dir * 128 + chain) * WSLOT;
    run_chain<FWD, SUP, FM>(smarr[grp], embase, tgbase, transitions, forb,
                            bnd_tr, bnd_forb, tlasts[grp], nrun, wsl);
}

__global__ __launch_bounds__(1024, 1) void crf_chain_kernel(
    const float* __restrict__ emissions,    // [B,T,N]
    const int* __restrict__ mask,           // [B,T]
    const int* __restrict__ target,         // [B,T,N]
    const float* __restrict__ transitions,  // [N,N]
    const float* __restrict__ start_tr,     // [N]
    const float* __restrict__ end_tr,       // [N]
    const int* __restrict__ forb,           // [N,N]
    const int* __restrict__ start_forb,     // [N]
    const int* __restrict__ end_forb,       // [N]
    float* __restrict__ ws)                 // [256*WSLOT]
{
    __shared__ SmemT sm[GROUPS];
    __shared__ int tl_sh[GROUPS];
    __shared__ int stats[2];  // [0] min tlast, [1] max nsteps

    const int dir = (int)blockIdx.x >> 5;          // 0..1
    const int mblk = (int)blockIdx.x & 31;         // 0..31
    const int chain0 = mblk << 2;                  // 4 chains per block
    const int sup = (mblk >= 16) ? 0 : 1;          // chains 0..63 sup
    const int tid = (int)threadIdx.x;
    const int grp = tid >> 8;
    const int gtid = tid & 255;
    const int gwave = gtid >> 6;
    const int lane = tid & 63;
    const int chain = chain0 + grp;
    const int b = chain & 63;

    // ---- per-group sequence length ----
    int lsum = 0;
    for (int k = gtid; k < T; k += 256) lsum += (mask[b * T + k] != 0);
    #pragma unroll
    for (int d = 1; d < 64; d <<= 1) lsum += __shfl_xor(lsum, d);
    if (lane == 0) sm[grp].lred[gwave] = lsum;
    if (tid == 0) { stats[0] = T; stats[1] = 0; }
    __syncthreads();
    const int tlast = (sm[grp].lred[0] + sm[grp].lred[1] +
                       sm[grp].lred[2] + sm[grp].lred[3]) - 1;
    if (gtid == 0) {
        tl_sh[grp] = tlast;
        atomicMin(&stats[0], tlast);   // LDS atomics: block-scope, capture-safe
        const int mid = tlast >> 1;
        const int ns = dir ? (tlast - mid) : mid;
        atomicMax(&stats[1], ns);
    }
    __syncthreads();
    const bool fm = (stats[0] == T - 1);
    const int nrun = stats[1];

    if (dir == 0) {
        if (sup) {
            if (fm) run_block<true, true, true>(sm, chain0, emissions, mask, target, transitions, start_tr, start_forb, forb, tl_sh, nrun, ws, dir);
            else    run_block<true, true, false>(sm, chain0, emissions, mask, target, transitions, start_tr, start_forb, forb, tl_sh, nrun, ws, dir);
        } else {
            if (fm) run_block<true, false, true>(sm, chain0, emissions, mask, target, transitions, start_tr, start_forb, forb, tl_sh, nrun, ws, dir);
            else    run_block<true, false, false>(sm, chain0, emissions, mask, target, transitions, start_tr, start_forb, forb, tl_sh, nrun, ws, dir);
        }
    } else {
        if (sup) {
            if (fm) run_block<false, true, true>(sm, chain0, emissions, mask, target, transitions, end_tr, end_forb, forb, tl_sh, nrun, ws, dir);
            else    run_block<false, true, false>(sm, chain0, emissions, mask, target, transitions, end_tr, end_forb, forb, tl_sh, nrun, ws, dir);
        } else {
            if (fm) run_block<false, false, true>(sm, chain0, emissions, mask, target, transitions, end_tr, end_forb, forb, tl_sh, nrun, ws, dir);
            else    run_block<false, false, false>(sm, chain0, emissions, mask, target, transitions, end_tr, end_forb, forb, tl_sh, nrun, ws, dir);
        }
    }
}

// One block per batch b; wave w handles chain c=w (sup/full):
// z_c = LN2*(Ma+Mb) + log(sum_i a_mid[i]*b_mid[i]); out[b] = z_1 - z_0.
__global__ void crf_dot_kernel(const float* __restrict__ ws,
                               float* __restrict__ out) {
    const int b = (int)blockIdx.x;     // 0..63
    const int tid = (int)threadIdx.x;  // 0..127
    const int w = tid >> 6;            // channel
    const int lane = tid & 63;
    const int chain = w * 64 + b;

    const float* fv = ws + (size_t)chain * WSLOT;          // fwd
    const float* bv = ws + (size_t)(128 + chain) * WSLOT;  // bwd

    float term = fv[lane] * bv[lane] + fv[lane + 64] * bv[lane + 64];
    #pragma unroll
    for (int d = 1; d < 64; d <<= 1) term += __shfl_xor(term, d);

    __shared__ float zz[2];
    if (lane == 0) zz[w] = LN2 * (fv[128] + bv[128]) + __logf(term);
    __syncthreads();
    if (tid == 0) out[b] = zz[1] - zz[0];
}

extern "C" void kernel_launch(void* const* d_in, const int* in_sizes, int n_in,
                              void* d_out, int out_size, void* d_ws, size_t ws_size,
                              hipStream_t stream) {
    const float* emissions = (const float*)d_in[0];
    const int* mask = (const int*)d_in[1];
    const int* target = (const int*)d_in[2];
    const float* transitions = (const float*)d_in[3];
    const float* start_tr = (const float*)d_in[4];
    const float* end_tr = (const float*)d_in[5];
    const int* forb = (const int*)d_in[6];
    const int* start_forb = (const int*)d_in[7];
    const int* end_forb = (const int*)d_in[8];
    float* out = (float*)d_out;
    float* ws = (float*)d_ws;

    crf_chain_kernel<<<dim3(64), dim3(1024), 0, stream>>>(
        emissions, mask, target, transitions, start_tr, end_tr,
        forb, start_forb, end_forb, ws);
    crf_dot_kernel<<<dim3(B), dim3(128), 0, stream>>>(ws, out);
}

// Round 17
// 617.810 us; speedup vs baseline: 1.6812x; 1.6812x over previous
//
#include <hip/hip_runtime.h>
#include <cstdint>
#include <cstddef>

#define IMPOSSIBLE -10000.0f
#define INV_LN2 1.44269504088896340736f
#define LN2 0.69314718055994530942f

constexpr int B = 64;
constexpr int T = 2048;
constexpr int N = 128;
constexpr int WSLOT = 132;  // 128 mid-vector + 1 scale + pad

typedef _Float16 h2 __attribute__((ext_vector_type(2)));
typedef _Float16 h8 __attribute__((ext_vector_type(8)));

typedef __attribute__((address_space(3))) uint32_t lds_u32_t;
typedef __attribute__((address_space(1))) const uint32_t g_u32_t;

__device__ __forceinline__ void gload_lds4(const void* g, void* l) {
    __builtin_amdgcn_global_load_lds((g_u32_t*)g, (lds_u32_t*)l, 4, 0, 0);
}

// ONE WAVE per chain-dir task; 256 blocks x 64 threads. Lane owns states
// j0=2l, j1=2l+1 (output columns). ZERO barriers: same-wave DS ops are
// in-order (write p at end of step t, read at t+1 is RAW-safe); DMA ring
// ordered by counted vmcnt only. No permlane: each lane computes the FULL
// 128-dot for its 2 columns (128 fdot2). Normalizer = readfirstlane of
// stot[state 0] (same-step component anchor -- no r7 stale-oscillator;
// p bounded ~e^2*90, f16-safe). Mtot += log2(anchor). E pairs in VGPRs
// (128 h2 regs); launch_bounds(64,1) -> 512-reg budget, no spill (r16's
// 1024-thr block made the compiler target 2 blk/CU and spill at 60 VGPR).
// Bidirectional (FWD template), SUP (target ring), FM (literal trip counts).
// Bool inputs are int32 per ABI. Pure function of d_in.
template<bool FWD, bool SUP, bool FM>
__device__ __forceinline__ void run_chain(
    _Float16* __restrict__ p_lds,          // [128]
    float (*__restrict__ ring_em)[128],    // [9][128]
    int (*__restrict__ ring_tg)[128],      // [9][128]
    const float* __restrict__ embase,
    const int* __restrict__ tgbase,
    const float* __restrict__ transitions,
    const int* __restrict__ forb,
    const float* __restrict__ bnd_tr,      // start_tr / end_tr
    const int* __restrict__ bnd_forb,      // start_forb / end_forb
    const int tlast_rt,
    float* __restrict__ wsl)
{
    const int lane = (int)threadIdx.x & 63;
    const int j0 = lane << 1, j1 = j0 + 1;

    const int tlast = FM ? (T - 1) : tlast_rt;
    const int mid = tlast >> 1;
    const int nsteps = FWD ? mid : (tlast - mid);

    // ---- E pairs: eA[m] pairs p(2m,2m+1) for column j0; eB for j1 ----
    // FWD: col j of E = E[i][j]. BWD: row j of E = E[j][i] (contiguous).
    h2 eA[64], eB[64];
    #pragma unroll
    for (int m = 0; m < 64; ++m) {
        float a0, a1, b0, b1;
        if (FWD) {
            const float2 r0 = *reinterpret_cast<const float2*>(&transitions[(2 * m) * N + j0]);
            const float2 r1 = *reinterpret_cast<const float2*>(&transitions[(2 * m + 1) * N + j0]);
            const int2 f0 = *reinterpret_cast<const int2*>(&forb[(2 * m) * N + j0]);
            const int2 f1 = *reinterpret_cast<const int2*>(&forb[(2 * m + 1) * N + j0]);
            a0 = f0.x ? 0.0f : __expf(r0.x);  a1 = f1.x ? 0.0f : __expf(r1.x);
            b0 = f0.y ? 0.0f : __expf(r0.y);  b1 = f1.y ? 0.0f : __expf(r1.y);
        } else {
            const float2 r0 = *reinterpret_cast<const float2*>(&transitions[j0 * N + 2 * m]);
            const float2 r1 = *reinterpret_cast<const float2*>(&transitions[j1 * N + 2 * m]);
            const int2 f0 = *reinterpret_cast<const int2*>(&forb[j0 * N + 2 * m]);
            const int2 f1 = *reinterpret_cast<const int2*>(&forb[j1 * N + 2 * m]);
            a0 = f0.x ? 0.0f : __expf(r0.x);  a1 = f0.y ? 0.0f : __expf(r0.y);
            b0 = f1.x ? 0.0f : __expf(r1.x);  b1 = f1.y ? 0.0f : __expf(r1.y);
        }
        eA[m] = h2{(_Float16)a0, (_Float16)a1};
        eB[m] = h2{(_Float16)b0, (_Float16)b1};
    }

    // ---- init at boundary ----
    const float2 bt2 = *reinterpret_cast<const float2*>(&bnd_tr[j0]);
    const int2 bf2 = *reinterpret_cast<const int2*>(&bnd_forb[j0]);
    const float bndA = bf2.x ? IMPOSSIBLE : bt2.x;
    const float bndB = bf2.y ? IMPOSSIBLE : bt2.y;
    const int r0r = FWD ? 0 : tlast;
    const float2 em02 = *reinterpret_cast<const float2*>(&embase[(size_t)r0r * N + j0]);
    int2 tg02 = make_int2(1, 1);
    if (SUP) tg02 = *reinterpret_cast<const int2*>(&tgbase[(size_t)r0r * N + j0]);
    const float v0l = ((tg02.x ? em02.x : IMPOSSIBLE) + bndA) * INV_LN2;
    const float v1l = ((tg02.y ? em02.y : IMPOSSIBLE) + bndB) * INV_LN2;

    float mx = fmaxf(v0l, v1l);
    #pragma unroll
    for (int d = 1; d < 64; d <<= 1) mx = fmaxf(mx, __shfl_xor(mx, d));
    float Mtot = rintf(mx);
    const float p00 = exp2f(v0l - Mtot);
    const float p01 = exp2f(v1l - Mtot);
    *reinterpret_cast<h2*>(&p_lds[j0]) = h2{(_Float16)p00, (_Float16)p01};

    // defaults when loop never hits t==mid (FWD mid==0 / BWD tlast==0)
    float svE0 = FWD ? p00 : __expf(bndA);
    float svE1 = FWD ? p01 : __expf(bndB);
    float svM = FWD ? Mtot : 0.0f;

    // ---- prologue DMA: 8 ring rows ahead ----
    #pragma unroll
    for (int s = 1; s <= 8; ++s) {
        int srow, drow;
        if (FWD) {
            srow = s; drow = s & 7;
        } else {
            const int r = tlast - s;
            const int ok = FM ? 1 : (r >= 0);
            srow = ok ? r : 0;
            drow = ok ? (r & 7) : 8;
        }
        const float* gse = embase + (size_t)srow * N + lane;
        gload_lds4(gse, &ring_em[drow][0]);
        gload_lds4(gse + 64, &ring_em[drow][64]);
        if (SUP) {
            const int* gst = tgbase + (size_t)srow * N + lane;
            gload_lds4(gst, &ring_tg[drow][0]);
            gload_lds4(gst + 64, &ring_tg[drow][64]);
        }
    }
    if (SUP) asm volatile("s_waitcnt vmcnt(24)" ::: "memory");
    else     asm volatile("s_waitcnt vmcnt(12)" ::: "memory");

    // fx for first iteration
    float fx0, fx1;
    {
        const int t1 = FWD ? 1 : (tlast - 1);
        const int rr = t1 & 7;
        const float2 emn = *reinterpret_cast<const float2*>(&ring_em[rr][j0]);
        int2 tgn = make_int2(1, 1);
        if (SUP) tgn = *reinterpret_cast<const int2*>(&ring_tg[rr][j0]);
        fx0 = (SUP && !tgn.x) ? 0.0f : __expf(emn.x);
        fx1 = (SUP && !tgn.y) ? 0.0f : __expf(emn.y);
    }

    const h8* pp = reinterpret_cast<const h8*>(p_lds);

    #pragma unroll 2
    for (int it = 0; it < nsteps; ++it) {
        const int t = FWD ? (1 + it) : (tlast - 1 - it);

        // issue DMA for row t+-8 (no barrier anywhere in this loop)
        {
            int srow, drow;
            if (FWD) {
                srow = t + 8; drow = srow & 7;
            } else {
                const int tt = t - 8;
                const int ok = (tt >= 0);
                srow = ok ? tt : 0;
                drow = ok ? (tt & 7) : 8;
            }
            const float* gse = embase + (size_t)srow * N + lane;
            gload_lds4(gse, &ring_em[drow][0]);
            gload_lds4(gse + 64, &ring_em[drow][64]);
            if (SUP) {
                const int* gst = tgbase + (size_t)srow * N + lane;
                gload_lds4(gst, &ring_tg[drow][0]);
                gload_lds4(gst + 64, &ring_tg[drow][64]);
            }
        }

        // hoisted uniform reads of the whole p array (in-order DS pipe:
        // sees last iteration's ds_write; single buffer is RAW-safe)
        h8 pvv[16];
        #pragma unroll
        for (int k = 0; k < 16; ++k) pvv[k] = pp[k];

        float a0 = 0.f, a1 = 0.f, a2 = 0.f, a3 = 0.f;   // column j0
        float b0 = 0.f, b1 = 0.f, b2 = 0.f, b3 = 0.f;   // column j1
        #pragma unroll
        for (int k = 0; k < 16; ++k) {
            const h8 pv = pvv[k];
            const h2 u0 = __builtin_shufflevector(pv, pv, 0, 1);
            const h2 u1 = __builtin_shufflevector(pv, pv, 2, 3);
            const h2 u2 = __builtin_shufflevector(pv, pv, 4, 5);
            const h2 u3 = __builtin_shufflevector(pv, pv, 6, 7);
            const int m = k << 2;
            a0 = __builtin_amdgcn_fdot2(u0, eA[m + 0], a0, false);
            a1 = __builtin_amdgcn_fdot2(u1, eA[m + 1], a1, false);
            a2 = __builtin_amdgcn_fdot2(u2, eA[m + 2], a2, false);
            a3 = __builtin_amdgcn_fdot2(u3, eA[m + 3], a3, false);
            b0 = __builtin_amdgcn_fdot2(u0, eB[m + 0], b0, false);
            b1 = __builtin_amdgcn_fdot2(u1, eB[m + 1], b1, false);
            b2 = __builtin_amdgcn_fdot2(u2, eB[m + 2], b2, false);
            b3 = __builtin_amdgcn_fdot2(u3, eB[m + 3], b3, false);
        }
        const float sA = (a0 + a1) + (a2 + a3);
        const float sB = (b0 + b1) + (b2 + b3);

        // same-step component anchor: stot of state 0 (lane 0's sA)
        const float anchor = fmaxf(
            __int_as_float(__builtin_amdgcn_readfirstlane(__float_as_int(sA))),
            1e-30f);
        const float sc = __builtin_amdgcn_rcpf(anchor);
        Mtot += __log2f(anchor);

        const float na0 = sA * (fx0 * sc);
        const float na1 = sB * (fx1 * sc);
        if (t == mid) {
            // FWD: alpha includes em_mid. BWD: beta excludes em_mid.
            svE0 = FWD ? na0 : (sA * sc);
            svE1 = FWD ? na1 : (sB * sc);
            svM = Mtot;
        }

        *reinterpret_cast<h2*>(&p_lds[j0]) = h2{(_Float16)na0, (_Float16)na1};

        // fx for next iteration from ring
        {
            const int nt = FWD ? (t + 1) : (t - 1);
            const int rr = nt & 7;
            const float2 emn = *reinterpret_cast<const float2*>(&ring_em[rr][j0]);
            int2 tgn = make_int2(1, 1);
            if (SUP) tgn = *reinterpret_cast<const int2*>(&ring_tg[rr][j0]);
            fx0 = (SUP && !tgn.x) ? 0.0f : __expf(emn.x);
            fx1 = (SUP && !tgn.y) ? 0.0f : __expf(emn.y);
        }

        // counted wait: never drains; keeps 6 slots in flight
        if (SUP) asm volatile("s_waitcnt vmcnt(24)" ::: "memory");
        else     asm volatile("s_waitcnt vmcnt(12)" ::: "memory");
    }

    // ---- write mid-vector + scale ----
    *reinterpret_cast<float2*>(&wsl[j0]) = make_float2(svE0, svE1);
    if (lane == 0) wsl[128] = svM;
}

__global__ __launch_bounds__(64, 1) void crf_chain_kernel(
    const float* __restrict__ emissions,    // [B,T,N]
    const int* __restrict__ mask,           // [B,T]
    const int* __restrict__ target,         // [B,T,N]
    const float* __restrict__ transitions,  // [N,N]
    const float* __restrict__ start_tr,     // [N]
    const float* __restrict__ end_tr,       // [N]
    const int* __restrict__ forb,           // [N,N]
    const int* __restrict__ start_forb,     // [N]
    const int* __restrict__ end_forb,       // [N]
    float* __restrict__ ws)                 // [256*WSLOT]
{
    __shared__ __align__(16) _Float16 p_lds[128];
    __shared__ __align__(16) float ring_em[9][128];
    __shared__ __align__(16) int ring_tg[9][128];

    const int dir = (int)blockIdx.x >> 7;   // 0 fwd, 1 bwd
    const int chain = (int)blockIdx.x & 127;
    const int c = chain >> 6;               // 0 = supervised, 1 = full
    const int b = chain & 63;
    const int lane = (int)threadIdx.x & 63;

    // ---- sequence length (single wave: shfl only) ----
    int lsum = 0;
    for (int k = lane; k < T; k += 64) lsum += (mask[b * T + k] != 0);
    #pragma unroll
    for (int d = 1; d < 64; d <<= 1) lsum += __shfl_xor(lsum, d);
    const int tlast = lsum - 1;
    const bool fm = (tlast == T - 1);

    const float* embase = emissions + (size_t)b * T * N;
    const int* tgbase = target + (size_t)b * T * N;
    float* wsl = ws + (size_t)(dir * 128 + chain) * WSLOT;

    if (dir == 0) {
        if (c == 0) {
            if (fm) run_chain<true, true, true>(p_lds, ring_em, ring_tg, embase, tgbase, transitions, forb, start_tr, start_forb, tlast, wsl);
            else    run_chain<true, true, false>(p_lds, ring_em, ring_tg, embase, tgbase, transitions, forb, start_tr, start_forb, tlast, wsl);
        } else {
            if (fm) run_chain<true, false, true>(p_lds, ring_em, ring_tg, embase, tgbase, transitions, forb, start_tr, start_forb, tlast, wsl);
            else    run_chain<true, false, false>(p_lds, ring_em, ring_tg, embase, tgbase, transitions, forb, start_tr, start_forb, tlast, wsl);
        }
    } else {
        if (c == 0) {
            if (fm) run_chain<false, true, true>(p_lds, ring_em, ring_tg, embase, tgbase, transitions, forb, end_tr, end_forb, tlast, wsl);
            else    run_chain<false, true, false>(p_lds, ring_em, ring_tg, embase, tgbase, transitions, forb, end_tr, end_forb, tlast, wsl);
        } else {
            if (fm) run_chain<false, false, true>(p_lds, ring_em, ring_tg, embase, tgbase, transitions, forb, end_tr, end_forb, tlast, wsl);
            else    run_chain<false, false, false>(p_lds, ring_em, ring_tg, embase, tgbase, transitions, forb, end_tr, end_forb, tlast, wsl);
        }
    }
}

// One block per batch b; wave w handles chain c=w (sup/full):
// z_c = LN2*(Ma+Mb) + log(sum_i a_mid[i]*b_mid[i]); out[b] = z_1 - z_0.
__global__ void crf_dot_kernel(const float* __restrict__ ws,
                               float* __restrict__ out) {
    const int b = (int)blockIdx.x;     // 0..63
    const int tid = (int)threadIdx.x;  // 0..127
    const int w = tid >> 6;            // channel
    const int lane = tid & 63;
    const int chain = w * 64 + b;

    const float* fv = ws + (size_t)chain * WSLOT;          // fwd
    const float* bv = ws + (size_t)(128 + chain) * WSLOT;  // bwd

    float term = fv[lane] * bv[lane] + fv[lane + 64] * bv[lane + 64];
    #pragma unroll
    for (int d = 1; d < 64; d <<= 1) term += __shfl_xor(term, d);

    __shared__ float zz[2];
    if (lane == 0) zz[w] = LN2 * (fv[128] + bv[128]) + __logf(term);
    __syncthreads();
    if (tid == 0) out[b] = zz[1] - zz[0];
}

extern "C" void kernel_launch(void* const* d_in, const int* in_sizes, int n_in,
                              void* d_out, int out_size, void* d_ws, size_t ws_size,
                              hipStream_t stream) {
    const float* emissions = (const float*)d_in[0];
    const int* mask = (const int*)d_in[1];
    const int* target = (const int*)d_in[2];
    const float* transitions = (const float*)d_in[3];
    const float* start_tr = (const float*)d_in[4];
    const float* end_tr = (const float*)d_in[5];
    const int* forb = (const int*)d_in[6];
    const int* start_forb = (const int*)d_in[7];
    const int* end_forb = (const int*)d_in[8];
    float* out = (float*)d_out;
    float* ws = (float*)d_ws;

    crf_chain_kernel<<<dim3(4 * B), dim3(64), 0, stream>>>(
        emissions, mask, target, transitions, start_tr, end_tr,
        forb, start_forb, end_forb, ws);
    crf_dot_kernel<<<dim3(B), dim3(128), 0, stream>>>(ws, out);
}

// Round 18
// 453.744 us; speedup vs baseline: 2.2891x; 1.3616x over previous
//
#include <hip/hip_runtime.h>
#include <cstdint>
#include <cstddef>

#define IMPOSSIBLE -10000.0f
#define INV_LN2 1.44269504088896340736f
#define LN2 0.69314718055994530942f

constexpr int B = 64;
constexpr int T = 2048;
constexpr int N = 128;
constexpr int WSLOT = 132;  // 128 mid-vector + 1 scale + pad

typedef _Float16 h2 __attribute__((ext_vector_type(2)));
typedef _Float16 h8 __attribute__((ext_vector_type(8)));

typedef __attribute__((address_space(3))) uint32_t lds_u32_t;
typedef __attribute__((address_space(1))) const uint32_t g_u32_t;

__device__ __forceinline__ void gload_lds4(const void* g, void* l) {
    __builtin_amdgcn_global_load_lds((g_u32_t*)g, (lds_u32_t*)l, 4, 0, 0);
}

struct SmemT {
    __align__(16) _Float16 p_buf[2][128];
    __align__(16) float ring_em[9][128];
    __align__(16) int ring_tg[9][128];
    float wred[4];
};

// r15 champion restored verbatim (454us). Bidirectional CRF, 4 waves/block,
// full compile-time specialization:
//  FWD: alpha from t=0 / beta from t=tlast (E-columns vs E-rows)
//  SUP: supervised channel (target ring, vmcnt(24)) vs full (vmcnt(12))
//  FM : full-mask fast path -> tlast/mid/nsteps literals (restores r11-grade
//       loop scheduling; runtime trip counts cost ~200ns/step, r14 evidence)
// Step: hoisted 8x rotated ds_read_b128 of f16 p, 64 v_dot2 (matvec+psum),
// permlane32_swap cross-half sums, self-referential psum normalizer
// (p' = s*fx/psum, unconditionally f16-bounded), em/tg DMA ring with counted
// vmcnt (never drains), one raw lgkmcnt+s_barrier per step.
// Per-step ~1060cy closes as: DS-broadcast 385 + VALU 320 + barrier 150 +
// latency 200 -- latency/DS-floor bound, no saturated pipe.
template<bool FWD, bool SUP, bool FM>
__device__ __forceinline__ void run_chain(
    SmemT& sm,
    const float* __restrict__ embase,
    const int* __restrict__ tgbase,
    const float* __restrict__ transitions,
    const int* __restrict__ forb,
    const float* __restrict__ bnd_tr,   // start_tr (fwd) / end_tr (bwd)
    const int* __restrict__ bnd_forb,   // start_forb / end_forb
    const int tlast_rt,
    float* __restrict__ wsl)
{
    const int tid = (int)threadIdx.x;
    const int wave = tid >> 6;
    const int lane = tid & 63;
    const int h = lane >> 5;
    const int j = (wave << 5) | (lane & 31);

    const int tlast = FM ? (T - 1) : tlast_rt;
    const int mid = tlast >> 1;
    const int nsteps = FWD ? mid : (tlast - mid);

    // ---- E slice in f16 pairs, pre-rotated by lane&7 ----
    // FWD: e = E[i][j] (column j); BWD: e = E[j][i] (row j)
    h2 e2[32];
    #pragma unroll
    for (int k = 0; k < 8; ++k) {
        const int cch = ((lane & 7) + k) & 7;
        const int ib = (h << 6) + (cch << 3);
        #pragma unroll
        for (int m = 0; m < 4; ++m) {
            const int i0 = ib + (m << 1);
            const int idx0 = FWD ? (i0 * N + j) : (j * N + i0);
            const int idx1 = FWD ? ((i0 + 1) * N + j) : (j * N + i0 + 1);
            const float f0 = forb[idx0] ? 0.0f : __expf(transitions[idx0]);
            const float f1 = forb[idx1] ? 0.0f : __expf(transitions[idx1]);
            e2[(k << 2) + m] = h2{(_Float16)f0, (_Float16)f1};
        }
    }

    // ---- init at boundary ----
    const float bnd = bnd_forb[j] ? IMPOSSIBLE : bnd_tr[j];
    const int r0 = FWD ? 0 : tlast;
    const float em0 = embase[(size_t)r0 * N + j];
    const int tg0 = SUP ? tgbase[(size_t)r0 * N + j] : 1;
    const float v0l = ((tg0 ? em0 : IMPOSSIBLE) + bnd) * INV_LN2;

    float mx = v0l;
    #pragma unroll
    for (int d = 1; d < 64; d <<= 1) mx = fmaxf(mx, __shfl_xor(mx, d));
    if (lane == 0) sm.wred[wave] = mx;
    __syncthreads();
    mx = fmaxf(fmaxf(sm.wred[0], sm.wred[1]), fmaxf(sm.wred[2], sm.wred[3]));

    float Mtot = rintf(mx);
    const float p0 = exp2f(v0l - Mtot);
    if (h == 0) sm.p_buf[0][j] = (_Float16)p0;

    // defaults when loop never hits t==mid (FWD mid==0 / BWD tlast==0)
    float svE = FWD ? p0 : __expf(bnd);
    float svM = FWD ? Mtot : 0.0f;

    // ---- prologue DMA: 8 ring rows ahead ----
    if (wave == 0) {
        #pragma unroll
        for (int s = 1; s <= 8; ++s) {
            int srow, drow;
            if (FWD) {
                srow = s; drow = s & 7;
            } else {
                const int r = tlast - s;
                const int ok = FM ? 1 : (r >= 0);   // FM: tlast-8 >= 2039
                srow = ok ? r : 0;
                drow = ok ? (r & 7) : 8;
            }
            const float* gse = embase + (size_t)srow * N + lane;
            gload_lds4(gse, &sm.ring_em[drow][0]);
            gload_lds4(gse + 64, &sm.ring_em[drow][64]);
            if (SUP) {
                const int* gst = tgbase + (size_t)srow * N + lane;
                gload_lds4(gst, &sm.ring_tg[drow][0]);
                gload_lds4(gst + 64, &sm.ring_tg[drow][64]);
            }
        }
        if (SUP) asm volatile("s_waitcnt vmcnt(24)" ::: "memory");
        else     asm volatile("s_waitcnt vmcnt(12)" ::: "memory");
    }
    __syncthreads();

    // fx for first iteration (FWD t=1; BWD t=tlast-1); unused if nsteps==0
    float fx;
    {
        const int t1 = FWD ? 1 : (tlast - 1);
        const int rr = t1 & 7;
        const float em_n = sm.ring_em[rr][j];
        if (SUP) {
            const int tg_n = sm.ring_tg[rr][j];
            fx = tg_n ? __expf(em_n) : 0.0f;
        } else {
            fx = __expf(em_n);
        }
    }

    const _Float16* pb0 = &sm.p_buf[0][h << 6];
    const _Float16* pb1 = &sm.p_buf[1][h << 6];
    const h2 one2 = h2{(_Float16)1.0f, (_Float16)1.0f};

    #pragma unroll 2
    for (int it = 0; it < nsteps; ++it) {
        const int t = FWD ? (1 + it) : (tlast - 1 - it);

        // raw barrier: drain LDS only; DMAs stay in flight
        asm volatile("s_waitcnt lgkmcnt(0)\n\ts_barrier" ::: "memory");

        // issue DMA for row t+-8 (FWD never OOB: t+8 <= mid+8 < T)
        if (wave == 0) {
            int srow, drow;
            if (FWD) {
                srow = t + 8; drow = srow & 7;
            } else {
                const int tt = t - 8;
                const int ok = (tt >= 0);
                srow = ok ? tt : 0;
                drow = ok ? (tt & 7) : 8;
            }
            const float* gse = embase + (size_t)srow * N + lane;
            gload_lds4(gse, &sm.ring_em[drow][0]);
            gload_lds4(gse + 64, &sm.ring_em[drow][64]);
            if (SUP) {
                const int* gst = tgbase + (size_t)srow * N + lane;
                gload_lds4(gst, &sm.ring_tg[drow][0]);
                gload_lds4(gst + 64, &sm.ring_tg[drow][64]);
            }
        }

        // parity: first iteration reads p_buf[0] (the init write)
        const int cur = (it & 1) ^ 1;
        const _Float16* pbase = (cur ^ 1) ? pb1 : pb0;

        // hoisted reads: all 8 ds_read_b128 issued before any use
        h8 pvv[8];
        #pragma unroll
        for (int k = 0; k < 8; ++k) {
            const int cch = ((lane & 7) + k) & 7;
            pvv[k] = *reinterpret_cast<const h8*>(pbase + (cch << 3));
        }

        float acc0 = 0.f, acc1 = 0.f, acc2 = 0.f, acc3 = 0.f;   // matvec
        float ps0 = 0.f, ps1 = 0.f, ps2 = 0.f, ps3 = 0.f;       // p half-sum
        #pragma unroll
        for (int k = 0; k < 8; ++k) {
            const h8 pv = pvv[k];
            const h2 w0 = __builtin_shufflevector(pv, pv, 0, 1);
            const h2 w1 = __builtin_shufflevector(pv, pv, 2, 3);
            const h2 w2 = __builtin_shufflevector(pv, pv, 4, 5);
            const h2 w3 = __builtin_shufflevector(pv, pv, 6, 7);
            acc0 = __builtin_amdgcn_fdot2(w0, e2[(k << 2) + 0], acc0, false);
            acc1 = __builtin_amdgcn_fdot2(w1, e2[(k << 2) + 1], acc1, false);
            acc2 = __builtin_amdgcn_fdot2(w2, e2[(k << 2) + 2], acc2, false);
            acc3 = __builtin_amdgcn_fdot2(w3, e2[(k << 2) + 3], acc3, false);
            ps0 = __builtin_amdgcn_fdot2(w0, one2, ps0, false);
            ps1 = __builtin_amdgcn_fdot2(w1, one2, ps1, false);
            ps2 = __builtin_amdgcn_fdot2(w2, one2, ps2, false);
            ps3 = __builtin_amdgcn_fdot2(w3, one2, ps3, false);
        }
        const float s = (acc0 + acc1) + (acc2 + acc3);
        const float ph = (ps0 + ps1) + (ps2 + ps3);

        // cross-half sums via permlane32_swap (VALU)
        float x = s, y = s;
        asm volatile("v_permlane32_swap_b32 %0, %1" : "+v"(x), "+v"(y));
        const float stot = x + y;
        float u = ph, v = ph;
        asm volatile("v_permlane32_swap_b32 %0, %1" : "+v"(u), "+v"(v));
        const float psum = fmaxf(u + v, 1e-30f);

        // self-referential rescale (off dependent path)
        const float sc = __builtin_amdgcn_rcpf(psum);
        Mtot += __log2f(psum);

        const float na = stot * (fx * sc);
        if (t == mid) {
            // FWD: alpha includes em_mid (post-fx). BWD: beta excludes em_mid.
            svE = FWD ? na : (stot * sc);
            svM = Mtot;
        }

        if (h == 0) sm.p_buf[cur][j] = (_Float16)na;

        // fx for next iteration from ring
        {
            const int nt = FWD ? (t + 1) : (t - 1);
            const int rr = nt & 7;
            const float em_n = sm.ring_em[rr][j];
            if (SUP) {
                const int tg_n = sm.ring_tg[rr][j];
                fx = tg_n ? __expf(em_n) : 0.0f;
            } else {
                fx = __expf(em_n);
            }
        }

        // counted wait: never drains; keeps 6 slots in flight
        if (wave == 0) {
            if (SUP) asm volatile("s_waitcnt vmcnt(24)" ::: "memory");
            else     asm volatile("s_waitcnt vmcnt(12)" ::: "memory");
        }
    }

    // ---- write mid-vector + scale to workspace ----
    if (h == 0) wsl[j] = svE;
    if (tid == 0) wsl[128] = svM;
}

__global__ __launch_bounds__(256, 1) void crf_chain_kernel(
    const float* __restrict__ emissions,    // [B,T,N]
    const int* __restrict__ mask,           // [B,T]
    const int* __restrict__ target,         // [B,T,N]
    const float* __restrict__ transitions,  // [N,N]
    const float* __restrict__ start_tr,     // [N]
    const float* __restrict__ end_tr,       // [N]
    const int* __restrict__ forb,           // [N,N]
    const int* __restrict__ start_forb,     // [N]
    const int* __restrict__ end_forb,       // [N]
    float* __restrict__ ws)                 // [256*WSLOT]
{
    __shared__ SmemT sm;
    __shared__ int lred[4];

    const int dir = (int)blockIdx.x >> 7;   // 0 fwd, 1 bwd
    const int chain = (int)blockIdx.x & 127;
    const int c = chain >> 6;               // 0 = supervised, 1 = full
    const int b = chain & 63;
    const int tid = (int)threadIdx.x;
    const int wave = tid >> 6;
    const int lane = tid & 63;

    // ---- sequence length (common) ----
    int lsum = 0;
    for (int k = tid; k < T; k += 256) lsum += (mask[b * T + k] != 0);
    #pragma unroll
    for (int d = 1; d < 64; d <<= 1) lsum += __shfl_xor(lsum, d);
    if (lane == 0) lred[wave] = lsum;
    __syncthreads();
    const int tlast = (lred[0] + lred[1] + lred[2] + lred[3]) - 1;
    const bool fm = (tlast == T - 1);

    const float* embase = emissions + (size_t)b * T * N;
    const int* tgbase = target + (size_t)b * T * N;
    float* wsl = ws + (size_t)(dir * 128 + chain) * WSLOT;

    if (dir == 0) {
        if (c == 0) {
            if (fm) run_chain<true, true, true>(sm, embase, tgbase, transitions, forb, start_tr, start_forb, tlast, wsl);
            else    run_chain<true, true, false>(sm, embase, tgbase, transitions, forb, start_tr, start_forb, tlast, wsl);
        } else {
            if (fm) run_chain<true, false, true>(sm, embase, tgbase, transitions, forb, start_tr, start_forb, tlast, wsl);
            else    run_chain<true, false, false>(sm, embase, tgbase, transitions, forb, start_tr, start_forb, tlast, wsl);
        }
    } else {
        if (c == 0) {
            if (fm) run_chain<false, true, true>(sm, embase, tgbase, transitions, forb, end_tr, end_forb, tlast, wsl);
            else    run_chain<false, true, false>(sm, embase, tgbase, transitions, forb, end_tr, end_forb, tlast, wsl);
        } else {
            if (fm) run_chain<false, false, true>(sm, embase, tgbase, transitions, forb, end_tr, end_forb, tlast, wsl);
            else    run_chain<false, false, false>(sm, embase, tgbase, transitions, forb, end_tr, end_forb, tlast, wsl);
        }
    }
}

// One block per batch b; wave w handles chain c=w (sup/full):
// z_c = LN2*(Ma+Mb) + log(sum_i a_mid[i]*b_mid[i]); out[b] = z_1 - z_0.
__global__ void crf_dot_kernel(const float* __restrict__ ws,
                               float* __restrict__ out) {
    const int b = (int)blockIdx.x;     // 0..63
    const int tid = (int)threadIdx.x;  // 0..127
    const int w = tid >> 6;            // channel
    const int lane = tid & 63;
    const int chain = w * 64 + b;

    const float* fv = ws + (size_t)chain * WSLOT;          // fwd
    const float* bv = ws + (size_t)(128 + chain) * WSLOT;  // bwd

    float term = fv[lane] * bv[lane] + fv[lane + 64] * bv[lane + 64];
    #pragma unroll
    for (int d = 1; d < 64; d <<= 1) term += __shfl_xor(term, d);

    __shared__ float zz[2];
    if (lane == 0) zz[w] = LN2 * (fv[128] + bv[128]) + __logf(term);
    __syncthreads();
    if (tid == 0) out[b] = zz[1] - zz[0];
}

extern "C" void kernel_launch(void* const* d_in, const int* in_sizes, int n_in,
                              void* d_out, int out_size, void* d_ws, size_t ws_size,
                              hipStream_t stream) {
    const float* emissions = (const float*)d_in[0];
    const int* mask = (const int*)d_in[1];
    const int* target = (const int*)d_in[2];
    const float* transitions = (const float*)d_in[3];
    const float* start_tr = (const float*)d_in[4];
    const float* end_tr = (const float*)d_in[5];
    const int* forb = (const int*)d_in[6];
    const int* start_forb = (const int*)d_in[7];
    const int* end_forb = (const int*)d_in[8];
    float* out = (float*)d_out;
    float* ws = (float*)d_ws;

    crf_chain_kernel<<<dim3(4 * B), dim3(256), 0, stream>>>(
        emissions, mask, target, transitions, start_tr, end_tr,
        forb, start_forb, end_forb, ws);
    crf_dot_kernel<<<dim3(B), dim3(128), 0, stream>>>(ws, out);
}